// Round 1
// baseline (305.831 us; speedup 1.0000x reference)
//
#include <hip/hip_runtime.h>
#include <hip/hip_bf16.h>
#include <stdint.h>

#define BATCH 8192
#define DIN   2048
#define DOUT  2048
#define NEXP  8
#define BM    128
#define BN    128
#define BK    64
#define LDK   72   // padded K stride in shorts (144 B = 9*16B, 2-way bank aliasing = free)

typedef __attribute__((ext_vector_type(4))) float fx4;
typedef __attribute__((ext_vector_type(8))) short sx8;
typedef __attribute__((ext_vector_type(4))) int   ix4;

__device__ __forceinline__ short f2b(float x){
  unsigned u = __float_as_uint(x);
  u = u + 0x7FFFu + ((u >> 16) & 1u);   // round-to-nearest-even
  return (short)(u >> 16);
}

// ---------------- bucket rows by expert ----------------
__global__ void prep_kernel(const int* __restrict__ actions, int* __restrict__ perm,
                            int* __restrict__ cnt_off){
  __shared__ int cnt[NEXP], off[NEXP], cur[NEXP];
  int t = threadIdx.x;
  if (t < NEXP) cnt[t] = 0;
  __syncthreads();
  for (int i = t; i < BATCH; i += 256) atomicAdd(&cnt[actions[i]], 1);
  __syncthreads();
  if (t == 0){ int s = 0; for (int e = 0; e < NEXP; ++e){ off[e] = s; cur[e] = s; s += cnt[e]; } }
  __syncthreads();
  for (int i = t; i < BATCH; i += 256){
    int e = actions[i];
    int p = atomicAdd(&cur[e], 1);
    perm[p] = i;
  }
  if (t < NEXP){ cnt_off[t] = cnt[t]; cnt_off[NEXP + t] = off[t]; }
}

// ---------------- W[e][k][n] f32 -> Wt[e][n][k] bf16 ----------------
__global__ void transw_kernel(const float* __restrict__ W, short* __restrict__ Wt){
  __shared__ float tile[64][65];
  int e  = blockIdx.z;
  int n0 = blockIdx.x * 64;
  int k0 = blockIdx.y * 64;
  const float* Wp = W  + (size_t)e * DIN * DOUT;
  short*       Wo = Wt + (size_t)e * DOUT * DIN;
  int t  = threadIdx.x;
  int lr = t >> 6;    // 0..3
  int lc = t & 63;    // 0..63
#pragma unroll
  for (int j = 0; j < 16; ++j){
    int k = j * 4 + lr;
    tile[k][lc] = Wp[(size_t)(k0 + k) * DOUT + n0 + lc];
  }
  __syncthreads();
#pragma unroll
  for (int j = 0; j < 16; ++j){
    int n = j * 4 + lr;
    Wo[(size_t)(n0 + n) * DIN + k0 + lc] = f2b(tile[lc][n]);
  }
}

// ---------------- pass-through metadata as f32 ----------------
__global__ void tail_kernel(const int* __restrict__ mxs, const int* __restrict__ actions,
                            float* __restrict__ out){
  int i = blockIdx.x * 256 + threadIdx.x;
  if (i < BATCH){
    out[(size_t)BATCH * DOUT + i]         = (float)mxs[i];
    out[(size_t)BATCH * DOUT + BATCH + i] = (float)actions[i];
  }
}

// ---------------- grouped GEMM: ys[perm] = bf16(xs[perm]) @ bf16(W[e]) + b[e] ----------------
__global__ __launch_bounds__(256, 2)
void moe_gemm_kernel(const float* __restrict__ xs, const short* __restrict__ Wt,
                     const float* __restrict__ bias, const int* __restrict__ perm,
                     const int* __restrict__ cnt_off, float* __restrict__ out){
  int e     = blockIdx.z;
  int cnt_e = cnt_off[e];
  int slot  = blockIdx.y;
  if (slot * BM >= cnt_e) return;
  int off_e  = cnt_off[NEXP + e];
  int m_base = off_e + slot * BM;
  int m_cnt  = min(BM, cnt_e - slot * BM);
  int n0     = blockIdx.x * BN;

  __shared__ short As[BM * LDK];
  __shared__ short Bs[BN * LDK];

  int t    = threadIdx.x;
  int wid  = t >> 6;
  int lane = t & 63;
  int wm   = wid & 1;        // wave row  (2)
  int wn   = wid >> 1;       // wave col  (2)
  int lrow = lane & 15;
  int lk   = lane >> 4;      // 0..3

  // staging assignment: thread covers row sr, K-half skh (32 elements)
  int sr  = t >> 1;          // 0..127
  int skh = (t & 1) * 32;    // 0 or 32

  int arow = (sr < m_cnt) ? perm[m_base + sr] : -1;
  const float* asrc = xs + (size_t)(arow < 0 ? 0 : arow) * DIN + skh;
  const short* bsrc = Wt + (size_t)e * DOUT * DIN + (size_t)(n0 + sr) * DIN + skh;

  fx4 acc[4][4];
#pragma unroll
  for (int i = 0; i < 4; ++i)
#pragma unroll
    for (int j = 0; j < 4; ++j)
      acc[i][j] = (fx4){0.f, 0.f, 0.f, 0.f};

  float bcol[4];
#pragma unroll
  for (int j = 0; j < 4; ++j)
    bcol[j] = bias[(size_t)e * DOUT + n0 + wn * 64 + j * 16 + lrow];

  const int NT = DIN / BK;   // 32 K-steps

  // prologue: load tile 0 into regs
  short sa[32];
  ix4 bv[4];
  {
    const fx4* ap = (const fx4*)asrc;
#pragma unroll
    for (int j = 0; j < 8; ++j){
      fx4 v = ap[j];
      sa[4*j+0] = f2b(v.x); sa[4*j+1] = f2b(v.y);
      sa[4*j+2] = f2b(v.z); sa[4*j+3] = f2b(v.w);
    }
    if (arow < 0){
#pragma unroll
      for (int j = 0; j < 32; ++j) sa[j] = 0;
    }
    const ix4* bp = (const ix4*)bsrc;
#pragma unroll
    for (int j = 0; j < 4; ++j) bv[j] = bp[j];
  }

  for (int ks = 0; ks < NT; ++ks){
    __syncthreads();   // previous compute done -> safe to overwrite LDS
    {
      ix4* adst = (ix4*)&As[sr * LDK + skh];
      ix4* bdst = (ix4*)&Bs[sr * LDK + skh];
#pragma unroll
      for (int j = 0; j < 4; ++j) adst[j] = ((const ix4*)sa)[j];
#pragma unroll
      for (int j = 0; j < 4; ++j) bdst[j] = bv[j];
    }
    __syncthreads();   // staging visible

    // issue next tile's global loads (overlap with MFMA below)
    if (ks + 1 < NT){
      const fx4* ap = (const fx4*)(asrc + (ks + 1) * BK);
#pragma unroll
      for (int j = 0; j < 8; ++j){
        fx4 v = ap[j];
        sa[4*j+0] = f2b(v.x); sa[4*j+1] = f2b(v.y);
        sa[4*j+2] = f2b(v.z); sa[4*j+3] = f2b(v.w);
      }
      if (arow < 0){
#pragma unroll
        for (int j = 0; j < 32; ++j) sa[j] = 0;
      }
      const ix4* bp = (const ix4*)(bsrc + (ks + 1) * BK);
#pragma unroll
      for (int j = 0; j < 4; ++j) bv[j] = bp[j];
    }

    // compute current tile
#pragma unroll
    for (int kk = 0; kk < 2; ++kk){
      sx8 af[4], bf[4];
#pragma unroll
      for (int i = 0; i < 4; ++i)
        af[i] = *(const sx8*)&As[(wm * 64 + i * 16 + lrow) * LDK + kk * 32 + lk * 8];
#pragma unroll
      for (int j = 0; j < 4; ++j)
        bf[j] = *(const sx8*)&Bs[(wn * 64 + j * 16 + lrow) * LDK + kk * 32 + lk * 8];
#pragma unroll
      for (int i = 0; i < 4; ++i)
#pragma unroll
        for (int j = 0; j < 4; ++j)
          acc[i][j] = __builtin_amdgcn_mfma_f32_16x16x32_bf16(af[i], bf[j], acc[i][j], 0, 0, 0);
    }
  }

  // epilogue: scatter rows back via perm, add bias
#pragma unroll
  for (int i = 0; i < 4; ++i){
    int rbase = wm * 64 + i * 16 + lk * 4;
    int prow[4];
#pragma unroll
    for (int q = 0; q < 4; ++q)
      prow[q] = (rbase + q < m_cnt) ? perm[m_base + rbase + q] : -1;
#pragma unroll
    for (int j = 0; j < 4; ++j){
      int col = n0 + wn * 64 + j * 16 + lrow;
      fx4 v = acc[i][j];
#pragma unroll
      for (int q = 0; q < 4; ++q)
        if (prow[q] >= 0)
          out[(size_t)prow[q] * DOUT + col] = v[q] + bcol[j];
    }
  }
}

extern "C" void kernel_launch(void* const* d_in, const int* in_sizes, int n_in,
                              void* d_out, int out_size, void* d_ws, size_t ws_size,
                              hipStream_t stream) {
  const float* xs      = (const float*)d_in[0];
  const float* W       = (const float*)d_in[1];
  const float* b       = (const float*)d_in[2];
  const int*   mxs     = (const int*)d_in[3];
  const int*   actions = (const int*)d_in[4];
  float* out = (float*)d_out;

  int*   perm    = (int*)d_ws;
  int*   cnt_off = perm + BATCH;
  short* Wt      = (short*)((char*)d_ws + 65536);   // 64 MB bf16 W^T

  hipLaunchKernelGGL(prep_kernel, dim3(1), dim3(256), 0, stream, actions, perm, cnt_off);
  hipLaunchKernelGGL(transw_kernel, dim3(DOUT/64, DIN/64, NEXP), dim3(256), 0, stream, W, Wt);
  hipLaunchKernelGGL(tail_kernel, dim3(BATCH/256), dim3(256), 0, stream, mxs, actions, out);
  hipLaunchKernelGGL(moe_gemm_kernel, dim3(DOUT/BN, BATCH/BM, NEXP), dim3(256), 0, stream,
                     xs, Wt, b, perm, cnt_off, out);
}

// Round 2
// 188.125 us; speedup vs baseline: 1.6257x; 1.6257x over previous
//
#include <hip/hip_runtime.h>
#include <hip/hip_bf16.h>
#include <stdint.h>

#define BATCH 8192
#define BATCH_PAD (BATCH + 128)
#define DIN   2048
#define DOUT  2048
#define NEXP  8
#define BM    128
#define BN    128
#define BK    64

typedef __attribute__((ext_vector_type(4))) float fx4;
typedef __attribute__((ext_vector_type(8))) short sx8;

__device__ __forceinline__ short f2b(float x){
  unsigned u = __float_as_uint(x);
  u = u + 0x7FFFu + ((u >> 16) & 1u);   // round-to-nearest-even
  return (short)(u >> 16);
}

__device__ __forceinline__ void gload16(const void* g, void* l){
  __builtin_amdgcn_global_load_lds(
      (const __attribute__((address_space(1))) unsigned int*)g,
      (__attribute__((address_space(3))) unsigned int*)l, 16, 0, 0);
}

// ---------------- bucket rows by expert ----------------
__global__ void prep_kernel(const int* __restrict__ actions, int* __restrict__ perm,
                            int* __restrict__ cnt_off){
  __shared__ int cnt[NEXP], off[NEXP], cur[NEXP];
  int t = threadIdx.x;
  if (t < NEXP) cnt[t] = 0;
  __syncthreads();
  for (int i = t; i < BATCH; i += 256) atomicAdd(&cnt[actions[i]], 1);
  __syncthreads();
  if (t == 0){ int s = 0; for (int e = 0; e < NEXP; ++e){ off[e] = s; cur[e] = s; s += cnt[e]; } }
  __syncthreads();
  for (int i = t; i < BATCH; i += 256){
    int e = actions[i];
    int p = atomicAdd(&cur[e], 1);
    perm[p] = i;
  }
  if (t < NEXP){ cnt_off[t] = cnt[t]; cnt_off[NEXP + t] = off[t]; }
}

// ---------------- gather + convert: xp[i][k] = bf16(xs[perm[i]][k]) ----------------
__global__ void gatherx_kernel(const float* __restrict__ xs, const int* __restrict__ perm,
                               short* __restrict__ xp){
  int i = blockIdx.x;          // padded row index
  int t = threadIdx.x;         // 256 threads, 8 elems each
  short v[8];
  if (i < BATCH){
    const fx4* src = (const fx4*)(xs + (size_t)perm[i] * DIN + t * 8);
    fx4 a = src[0], b2 = src[1];
    v[0]=f2b(a.x); v[1]=f2b(a.y); v[2]=f2b(a.z); v[3]=f2b(a.w);
    v[4]=f2b(b2.x); v[5]=f2b(b2.y); v[6]=f2b(b2.z); v[7]=f2b(b2.w);
  } else {
#pragma unroll
    for (int j = 0; j < 8; ++j) v[j] = 0;
  }
  *(sx8*)(xp + (size_t)i * DIN + t * 8) = *(const sx8*)v;
}

// ---------------- W[e][k][n] f32 -> Wt[e][n][k] bf16 ----------------
__global__ void transw_kernel(const float* __restrict__ W, short* __restrict__ Wt){
  __shared__ float tile[64][65];
  int e  = blockIdx.z;
  int n0 = blockIdx.x * 64;
  int k0 = blockIdx.y * 64;
  const float* Wp = W  + (size_t)e * DIN * DOUT;
  short*       Wo = Wt + (size_t)e * DOUT * DIN;
  int t  = threadIdx.x;
  int lr = t >> 6;    // 0..3
  int lc = t & 63;    // 0..63
#pragma unroll
  for (int j = 0; j < 16; ++j){
    int k = j * 4 + lr;
    tile[k][lc] = Wp[(size_t)(k0 + k) * DOUT + n0 + lc];
  }
  __syncthreads();
#pragma unroll
  for (int j = 0; j < 16; ++j){
    int n = j * 4 + lr;
    Wo[(size_t)(n0 + n) * DIN + k0 + lc] = f2b(tile[lc][n]);
  }
}

// ---------------- pass-through metadata as f32 ----------------
__global__ void tail_kernel(const int* __restrict__ mxs, const int* __restrict__ actions,
                            float* __restrict__ out){
  int i = blockIdx.x * 256 + threadIdx.x;
  if (i < BATCH){
    out[(size_t)BATCH * DOUT + i]         = (float)mxs[i];
    out[(size_t)BATCH * DOUT + BATCH + i] = (float)actions[i];
  }
}

// ---------------- grouped GEMM (m97 structure): out[perm] = xp @ Wt[e]^T + b[e] ----------------
__global__ __launch_bounds__(256)
void moe_gemm_kernel(const short* __restrict__ xp, const short* __restrict__ Wt,
                     const float* __restrict__ bias, const int* __restrict__ perm,
                     const int* __restrict__ cnt_off, float* __restrict__ out){
  int e     = blockIdx.z;
  int cnt_e = cnt_off[e];
  int slot  = blockIdx.y;
  if (slot * BM >= cnt_e) return;
  int off_e  = cnt_off[NEXP + e];
  int m_base = off_e + slot * BM;
  int m_cnt  = min(BM, cnt_e - slot * BM);
  int n0     = blockIdx.x * BN;

  __shared__ short As[BM * BK];   // [row][k] linear, 16 KB
  __shared__ short Bs[BN * BK];   // [n][k]   linear, 16 KB

  int t    = threadIdx.x;
  int wid  = t >> 6;
  int lane = t & 63;
  int wm   = wid & 1;        // wave row  (2)
  int wn   = wid >> 1;       // wave col  (2)
  int lrow = lane & 15;
  int lk   = lane >> 4;      // 0..3

  // staging: thread t covers row (q*32 + wid*8 + lane/8), 16B chunk (lane&7)
  int srow   = wid * 8 + (lane >> 3);
  int schunk = lane & 7;
  const char* ab = (const char*)xp + ((size_t)(m_base + srow) * DIN + schunk * 8) * 2;
  const char* bb = (const char*)Wt + ((size_t)e * DOUT * DIN + (size_t)(n0 + srow) * DIN + schunk * 8) * 2;

  fx4 acc[4][4];
#pragma unroll
  for (int i = 0; i < 4; ++i)
#pragma unroll
    for (int j = 0; j < 4; ++j)
      acc[i][j] = (fx4){0.f, 0.f, 0.f, 0.f};

  float bcol[4];
#pragma unroll
  for (int j = 0; j < 4; ++j)
    bcol[j] = bias[(size_t)e * DOUT + n0 + wn * 64 + j * 16 + lrow];

  const int NT = DIN / BK;   // 32 K-steps

  for (int ks = 0; ks < NT; ++ks){
    size_t ko = (size_t)ks * BK * 2;   // byte offset along K
#pragma unroll
    for (int q = 0; q < 4; ++q)
      gload16(ab + (size_t)q * 32 * (DIN * 2) + ko, &As[q * 2048 + t * 8]);
#pragma unroll
    for (int q = 0; q < 4; ++q)
      gload16(bb + (size_t)q * 32 * (DIN * 2) + ko, &Bs[q * 2048 + t * 8]);

    __syncthreads();   // staging visible (compiler drains vmcnt before barrier)

#pragma unroll
    for (int kk = 0; kk < 2; ++kk){
      sx8 af[4], bfr[4];
#pragma unroll
      for (int i = 0; i < 4; ++i)
        af[i] = *(const sx8*)&As[(wm * 64 + i * 16 + lrow) * BK + kk * 32 + lk * 8];
#pragma unroll
      for (int j = 0; j < 4; ++j)
        bfr[j] = *(const sx8*)&Bs[(wn * 64 + j * 16 + lrow) * BK + kk * 32 + lk * 8];
#pragma unroll
      for (int i = 0; i < 4; ++i)
#pragma unroll
        for (int j = 0; j < 4; ++j)
          acc[i][j] = __builtin_amdgcn_mfma_f32_16x16x32_bf16(af[i], bfr[j], acc[i][j], 0, 0, 0);
    }

    __syncthreads();   // compute done -> safe to overwrite LDS next iter
  }

  // epilogue: scatter rows back via perm, add bias
#pragma unroll
  for (int i = 0; i < 4; ++i){
    int rbase = wm * 64 + i * 16 + lk * 4;
    int prow[4];
#pragma unroll
    for (int q = 0; q < 4; ++q)
      prow[q] = (rbase + q < m_cnt) ? perm[m_base + rbase + q] : -1;
#pragma unroll
    for (int j = 0; j < 4; ++j){
      int col = n0 + wn * 64 + j * 16 + lrow;
      fx4 v = acc[i][j];
#pragma unroll
      for (int q = 0; q < 4; ++q)
        if (prow[q] >= 0)
          out[(size_t)prow[q] * DOUT + col] = v[q] + bcol[j];
    }
  }
}

extern "C" void kernel_launch(void* const* d_in, const int* in_sizes, int n_in,
                              void* d_out, int out_size, void* d_ws, size_t ws_size,
                              hipStream_t stream) {
  const float* xs      = (const float*)d_in[0];
  const float* W       = (const float*)d_in[1];
  const float* b       = (const float*)d_in[2];
  const int*   mxs     = (const int*)d_in[3];
  const int*   actions = (const int*)d_in[4];
  float* out = (float*)d_out;

  int*   perm    = (int*)d_ws;
  int*   cnt_off = perm + BATCH;
  short* Wt      = (short*)((char*)d_ws + 65536);                      // 64 MB bf16 W^T
  short* xp      = (short*)((char*)d_ws + 65536 + (size_t)NEXP * DIN * DOUT * 2); // 34 MB gathered bf16 x

  hipLaunchKernelGGL(prep_kernel, dim3(1), dim3(256), 0, stream, actions, perm, cnt_off);
  hipLaunchKernelGGL(gatherx_kernel, dim3(BATCH_PAD), dim3(256), 0, stream, xs, perm, xp);
  hipLaunchKernelGGL(transw_kernel, dim3(DOUT/64, DIN/64, NEXP), dim3(256), 0, stream, W, Wt);
  hipLaunchKernelGGL(tail_kernel, dim3(BATCH/256), dim3(256), 0, stream, mxs, actions, out);
  hipLaunchKernelGGL(moe_gemm_kernel, dim3(DOUT/BN, 64, NEXP), dim3(256), 0, stream,
                     xp, Wt, b, perm, cnt_off, out);
}

// Round 3
// 187.485 us; speedup vs baseline: 1.6312x; 1.0034x over previous
//
#include <hip/hip_runtime.h>
#include <hip/hip_bf16.h>
#include <stdint.h>

#define BATCH 8192
#define BATCH_PAD (BATCH + 128)
#define DIN   2048
#define DOUT  2048
#define NEXP  8
#define BM    128
#define BN    256
#define BK    64
#define NT    (DIN / BK)      // 32 K-tiles
#define ASZ   16384           // A region bytes per buffer (128 x 64 x 2)
#define TSZ   49152           // per-buffer bytes: A 16K + B 32K

typedef __attribute__((ext_vector_type(4))) float fx4;
typedef __attribute__((ext_vector_type(8))) short sx8;

__device__ __forceinline__ short f2b(float x){
  unsigned u = __float_as_uint(x);
  u = u + 0x7FFFu + ((u >> 16) & 1u);   // round-to-nearest-even
  return (short)(u >> 16);
}

__device__ __forceinline__ void gload16(const void* g, void* l){
  __builtin_amdgcn_global_load_lds(
      (const __attribute__((address_space(1))) unsigned int*)g,
      (__attribute__((address_space(3))) unsigned int*)l, 16, 0, 0);
}

// ---------------- bucket rows by expert (+ metadata tail) ----------------
__global__ void prep_kernel(const int* __restrict__ actions, const int* __restrict__ mxs,
                            int* __restrict__ perm, int* __restrict__ cnt_off,
                            float* __restrict__ out){
  __shared__ int cnt[NEXP], off[NEXP], cur[NEXP];
  int t = threadIdx.x;
  if (t < NEXP) cnt[t] = 0;
  __syncthreads();
  for (int i = t; i < BATCH; i += 256){
    atomicAdd(&cnt[actions[i]], 1);
    out[(size_t)BATCH * DOUT + i]         = (float)mxs[i];
    out[(size_t)BATCH * DOUT + BATCH + i] = (float)actions[i];
  }
  __syncthreads();
  if (t == 0){ int s = 0; for (int e = 0; e < NEXP; ++e){ off[e] = s; cur[e] = s; s += cnt[e]; } }
  __syncthreads();
  for (int i = t; i < BATCH; i += 256){
    int e = actions[i];
    int p = atomicAdd(&cur[e], 1);
    perm[p] = i;
  }
  if (t < NEXP){ cnt_off[t] = cnt[t]; cnt_off[NEXP + t] = off[t]; }
}

// ---------------- gather + convert: xp[i][k] = bf16(xs[perm[i]][k]) ----------------
__global__ void gatherx_kernel(const float* __restrict__ xs, const int* __restrict__ perm,
                               short* __restrict__ xp){
  int i = blockIdx.x;          // padded row index
  int t = threadIdx.x;         // 256 threads, 8 elems each
  short v[8];
  if (i < BATCH){
    const fx4* src = (const fx4*)(xs + (size_t)perm[i] * DIN + t * 8);
    fx4 a = src[0], b2 = src[1];
    v[0]=f2b(a.x); v[1]=f2b(a.y); v[2]=f2b(a.z); v[3]=f2b(a.w);
    v[4]=f2b(b2.x); v[5]=f2b(b2.y); v[6]=f2b(b2.z); v[7]=f2b(b2.w);
  } else {
#pragma unroll
    for (int j = 0; j < 8; ++j) v[j] = 0;
  }
  *(sx8*)(xp + (size_t)i * DIN + t * 8) = *(const sx8*)v;
}

// ---------------- W[e][k][n] f32 -> Wt[e][n][k] bf16 ----------------
__global__ void transw_kernel(const float* __restrict__ W, short* __restrict__ Wt){
  __shared__ float tile[64][69];
  int e  = blockIdx.z;
  int n0 = blockIdx.x * 64;
  int k0 = blockIdx.y * 64;
  const float* Wp = W + (size_t)e * DIN * DOUT + (size_t)k0 * DOUT + n0;
  int t = threadIdx.x;   // 256
#pragma unroll
  for (int it = 0; it < 4; ++it){
    int r = it * 16 + (t >> 4);
    int c = (t & 15) * 4;
    fx4 v = *(const fx4*)(Wp + (size_t)r * DOUT + c);
    tile[r][c] = v.x; tile[r][c+1] = v.y; tile[r][c+2] = v.z; tile[r][c+3] = v.w;
  }
  __syncthreads();
  int n  = t >> 2;
  int kc = (t & 3) * 16;
  short vv[16];
#pragma unroll
  for (int j = 0; j < 16; ++j) vv[j] = f2b(tile[kc + j][n]);
  short* dst = Wt + (size_t)e * DOUT * DIN + (size_t)(n0 + n) * DIN + k0 + kc;
  *(sx8*)dst       = *(const sx8*)vv;
  *(sx8*)(dst + 8) = *(const sx8*)(vv + 8);
}

// ---------------- grouped GEMM: triple-buffered pipelined MFMA ----------------
__global__ __launch_bounds__(512, 2)
void moe_gemm_kernel(const short* __restrict__ xp, const short* __restrict__ Wt,
                     const float* __restrict__ bias, const int* __restrict__ perm,
                     const int* __restrict__ cnt_off, float* __restrict__ out){
  extern __shared__ char lds[];

  // bijective XCD swizzle: J = (F%8)*512 + F/8 ; J = g*64 + slot, g = e*8 + nb
  int F    = blockIdx.x;
  int J    = (F & 7) * 512 + (F >> 3);
  int g    = J >> 6;
  int slot = J & 63;
  int e    = g >> 3;
  int nb   = g & 7;
  int cnt_e = cnt_off[e];
  if (slot * BM >= cnt_e) return;
  int off_e  = cnt_off[NEXP + e];
  int m_base = off_e + slot * BM;
  int m_cnt  = min(BM, cnt_e - slot * BM);
  int n0     = nb * BN;

  int t    = threadIdx.x;
  int wid  = t >> 6;
  int l    = t & 63;
  int wm   = wid & 1;          // 2 wave rows
  int wn   = wid >> 1;         // 4 wave cols
  int lrow = l & 15;
  int lk   = l >> 4;

  // ---- stage source pointers (pre-swizzled global col) ----
  int csrc = (((t & 7) ^ ((t >> 3) & 7)) << 4);
  const char* agp[2];
  const char* bgp[4];
  {
    const char* xpB = (const char*)xp;
    const char* wtB = (const char*)Wt + (size_t)e * ((size_t)DOUT * DIN * 2);
#pragma unroll
    for (int j = 0; j < 2; ++j){
      int r = j * 64 + (t >> 3);
      agp[j] = xpB + (size_t)(m_base + r) * (DIN * 2) + csrc;
    }
#pragma unroll
    for (int j = 0; j < 4; ++j){
      int r = j * 64 + (t >> 3);
      bgp[j] = wtB + (size_t)(n0 + r) * (DIN * 2) + csrc;
    }
  }
  int da0 = t * 16,        da1 = 8192  + t * 16;
  int db0 = ASZ + t * 16,  db1 = ASZ + 8192 + t * 16;
  int db2 = ASZ + 16384 + t * 16, db3 = ASZ + 24576 + t * 16;

#define STG1(kt, base) do{ gload16(agp[0] + (size_t)(kt)*128, lds + (base) + da0); \
                           gload16(agp[1] + (size_t)(kt)*128, lds + (base) + da1); \
                           gload16(bgp[0] + (size_t)(kt)*128, lds + (base) + db0);}while(0)
#define STG2(kt, base) do{ gload16(bgp[1] + (size_t)(kt)*128, lds + (base) + db1); \
                           gload16(bgp[2] + (size_t)(kt)*128, lds + (base) + db2); \
                           gload16(bgp[3] + (size_t)(kt)*128, lds + (base) + db3);}while(0)

  // ---- fragment lane offsets (XOR-swizzled) ----
  int sw = (lrow & 7) << 4;
  int aoff[2][4], boff[2][4];
#pragma unroll
  for (int kk = 0; kk < 2; ++kk){
#pragma unroll
    for (int m = 0; m < 4; ++m)
      aoff[kk][m] = (wm * 64 + m * 16 + lrow) * 128 + (((kk * 4 + lk) * 16) ^ sw);
#pragma unroll
    for (int n = 0; n < 4; ++n)
      boff[kk][n] = ASZ + (wn * 64 + n * 16 + lrow) * 128 + (((kk * 4 + lk) * 16) ^ sw);
  }

  fx4 acc[4][4];
#pragma unroll
  for (int m = 0; m < 4; ++m)
#pragma unroll
    for (int n = 0; n < 4; ++n)
      acc[m][n] = (fx4){0.f, 0.f, 0.f, 0.f};

  float bcol[4];
#pragma unroll
  for (int n = 0; n < 4; ++n)
    bcol[n] = bias[(size_t)e * DOUT + n0 + wn * 64 + n * 16 + lrow];

  // ---- prologue: stage tiles 0,1 ----
  STG1(0, 0);     STG2(0, 0);
  STG1(1, TSZ);   STG2(1, TSZ);
  asm volatile("s_waitcnt vmcnt(6)" ::: "memory");   // tile 0 landed
  __builtin_amdgcn_s_barrier();
  asm volatile("" ::: "memory");

  sx8 a0[4], a1[4], b0[4], b1[4];
#pragma unroll
  for (int m = 0; m < 4; ++m) a0[m] = *(const sx8*)(lds + aoff[0][m]);
#pragma unroll
  for (int n = 0; n < 4; ++n) b0[n] = *(const sx8*)(lds + boff[0][n]);

  int cmp = 0, nxt = TSZ, stg = 2 * TSZ;

  for (int kt = 0; kt < NT; ++kt){
    // ---- P1: read kk1 frags | stage half of tile kt+2 | MFMA kk0 ----
#pragma unroll
    for (int m = 0; m < 4; ++m) a1[m] = *(const sx8*)(lds + cmp + aoff[1][m]);
#pragma unroll
    for (int n = 0; n < 4; ++n) b1[n] = *(const sx8*)(lds + cmp + boff[1][n]);
    if (kt + 2 < NT) STG1(kt + 2, stg);
    __builtin_amdgcn_s_setprio(1);
#pragma unroll
    for (int m = 0; m < 4; ++m)
#pragma unroll
      for (int n = 0; n < 4; ++n)
        acc[m][n] = __builtin_amdgcn_mfma_f32_16x16x32_bf16(a0[m], b0[n], acc[m][n], 0, 0, 0);
    __builtin_amdgcn_s_setprio(0);
    __builtin_amdgcn_s_barrier();
    asm volatile("" ::: "memory");

    // ---- P2: stage rest | counted vmcnt | read next-tile kk0 | MFMA kk1 ----
    if (kt + 2 < NT){
      STG2(kt + 2, stg);
      asm volatile("s_waitcnt vmcnt(6)" ::: "memory");  // tile kt+1 landed, kt+2 in flight
    } else {
      asm volatile("s_waitcnt vmcnt(0)" ::: "memory");
    }
    __builtin_amdgcn_s_barrier();
    asm volatile("" ::: "memory");
    if (kt + 1 < NT){
#pragma unroll
      for (int m = 0; m < 4; ++m) a0[m] = *(const sx8*)(lds + nxt + aoff[0][m]);
#pragma unroll
      for (int n = 0; n < 4; ++n) b0[n] = *(const sx8*)(lds + nxt + boff[0][n]);
    }
    __builtin_amdgcn_s_setprio(1);
#pragma unroll
    for (int m = 0; m < 4; ++m)
#pragma unroll
      for (int n = 0; n < 4; ++n)
        acc[m][n] = __builtin_amdgcn_mfma_f32_16x16x32_bf16(a1[m], b1[n], acc[m][n], 0, 0, 0);
    __builtin_amdgcn_s_setprio(0);
    __builtin_amdgcn_s_barrier();
    asm volatile("" ::: "memory");

    int tmp = cmp; cmp = nxt; nxt = stg; stg = tmp;
  }

  // ---- epilogue: scatter rows via perm, add bias ----
#pragma unroll
  for (int m = 0; m < 4; ++m){
    int rb = wm * 64 + m * 16 + lk * 4;
    int prow[4];
#pragma unroll
    for (int q = 0; q < 4; ++q)
      prow[q] = (rb + q < m_cnt) ? perm[m_base + rb + q] : -1;
#pragma unroll
    for (int n = 0; n < 4; ++n){
      int col = n0 + wn * 64 + n * 16 + lrow;
      fx4 v = acc[m][n];
#pragma unroll
      for (int q = 0; q < 4; ++q)
        if (prow[q] >= 0)
          out[(size_t)prow[q] * DOUT + col] = v[q] + bcol[n];
    }
  }
#undef STG1
#undef STG2
}

extern "C" void kernel_launch(void* const* d_in, const int* in_sizes, int n_in,
                              void* d_out, int out_size, void* d_ws, size_t ws_size,
                              hipStream_t stream) {
  const float* xs      = (const float*)d_in[0];
  const float* W       = (const float*)d_in[1];
  const float* b       = (const float*)d_in[2];
  const int*   mxs     = (const int*)d_in[3];
  const int*   actions = (const int*)d_in[4];
  float* out = (float*)d_out;

  int*   perm    = (int*)d_ws;
  int*   cnt_off = perm + BATCH;
  short* Wt      = (short*)((char*)d_ws + 65536);                                   // 64 MB bf16 W^T
  short* xp      = (short*)((char*)d_ws + 65536 + (size_t)NEXP * DIN * DOUT * 2);   // 34 MB gathered bf16 x

  hipLaunchKernelGGL(prep_kernel, dim3(1), dim3(256), 0, stream, actions, mxs, perm, cnt_off, out);
  hipLaunchKernelGGL(gatherx_kernel, dim3(BATCH_PAD), dim3(256), 0, stream, xs, perm, xp);
  hipLaunchKernelGGL(transw_kernel, dim3(DOUT/64, DIN/64, NEXP), dim3(256), 0, stream, W, Wt);
  hipLaunchKernelGGL(moe_gemm_kernel, dim3(64 * 64), dim3(512), 147456, stream,
                     xp, Wt, b, perm, cnt_off, out);
}